// Round 7
// baseline (130.780 us; speedup 1.0000x reference)
//
#include <hip/hip_runtime.h>
#include <hip/hip_bf16.h>
#include <stdint.h>

namespace {
constexpr int Bb   = 8;
constexpr int Ff   = 64;
constexpr int Ee   = 49152;
constexpr int Vv   = 16384;
constexpr int TWOE = 2 * Ee;      // 98304
constexpr int MID  = 96;
constexpr int OUTC = 64;
}

typedef __attribute__((ext_vector_type(8))) short bf16x8;
typedef __attribute__((ext_vector_type(4))) float f32x4;
typedef __attribute__((ext_vector_type(4))) unsigned int u32x4;

// ---------- zero counters + pack weights into MFMA B-fragment order (one launch) ----------
__global__ void prep_misc(const float* __restrict__ W1, const float* __restrict__ W2,
                          __hip_bfloat16* __restrict__ w1f, __hip_bfloat16* __restrict__ w2f,
                          int* __restrict__ cnt) {
    int tid = blockIdx.x * 256 + threadIdx.x;   // 0 .. 24575
    if (tid < Vv) cnt[tid] = 0;
    if (tid < 18432) {
        int j = tid & 7, l = (tid >> 3) & 63, ft = tid >> 9;   // ft = kk*6+nt
        int kk = ft / 6, nt = ft - kk * 6;
        int k = kk * 32 + (l >> 4) * 8 + j;
        int n = nt * 16 + (l & 15);
        w1f[tid] = __float2bfloat16(W1[k * MID + n]);
    } else if (tid < 24576) {
        int t2 = tid - 18432;
        int j = t2 & 7, l = (t2 >> 3) & 63, ft = t2 >> 9;      // ft = kk*4+nt
        int kk = ft >> 2, nt = ft & 3;
        int k = kk * 32 + (l >> 4) * 8 + j;
        int n = nt * 16 + (l & 15);
        w2f[t2] = __float2bfloat16(W2[k * OUTC + n]);
    }
}

// ---------- build occurrence buckets ----------
__global__ void bucket_fill(const int* __restrict__ conn, int* __restrict__ cnt,
                            int* __restrict__ buckets) {
    int i = blockIdx.x * 256 + threadIdx.x;
    if (i >= TWOE) return;
    int v = conn[i];
    int pos = atomicAdd(&cnt[v], 1);
    if (pos < 6) buckets[v * 6 + pos] = i;
}

// ---------- sort the 6 indices per vertex, emit inverse perm dest[i] = v*6 + slot ----------
__global__ void sort6_inv(const int* __restrict__ buckets, int* __restrict__ dest) {
    int v = blockIdx.x * 256 + threadIdx.x;
    if (v >= Vv) return;
    int a[6];
#pragma unroll
    for (int k = 0; k < 6; ++k) a[k] = buckets[v * 6 + k];
#define CSWAP(x, y) { int lo = min(a[x], a[y]); int hi = max(a[x], a[y]); a[x] = lo; a[y] = hi; }
    CSWAP(1, 2) CSWAP(4, 5) CSWAP(0, 2) CSWAP(3, 5) CSWAP(0, 1) CSWAP(3, 4)
    CSWAP(2, 5) CSWAP(0, 3) CSWAP(1, 4) CSWAP(2, 4) CSWAP(1, 3) CSWAP(2, 3)
#undef CSWAP
#pragma unroll
    for (int k = 0; k < 6; ++k) dest[a[k]] = v * 6 + k;
}

// ---------- transpose + permute, batch-fused ----------
// Block = 16 e-values x 64 channels x 8 batches. xg layout: [v*6+slot][b][32] bf16,
// so each endpoint emits ONE contiguous aligned 512B random write (8 b x 64B).
__global__ __launch_bounds__(256) void scatter_feats(const float* __restrict__ feat,
                                                     const int* __restrict__ dest,
                                                     ushort* __restrict__ xg) {
    // tile ushort offsets: off(e,b,h,cc) = e*648 + b*80 + h*40 + cc  (all 16B-aligned strides)
    __shared__ __align__(16) ushort tile[16 * 648];   // 20.25 KB
    const int t  = threadIdx.x;
    const int e0 = blockIdx.x * 16;
    const int c  = t >> 2;          // channel 0..63
    const int l4 = t & 3;           // e-quad 0..3
    const int hc = c >> 5, cc = c & 31;
#pragma unroll
    for (int b = 0; b < 8; ++b) {
        float4 d = *reinterpret_cast<const float4*>(feat + ((size_t)b * Ff + c) * Ee + e0 + l4 * 4);
        int base = b * 80 + hc * 40 + cc;
        float vals[4] = {d.x, d.y, d.z, d.w};
#pragma unroll
        for (int j = 0; j < 4; ++j) {
            __hip_bfloat16 hv = __float2bfloat16(vals[j]);
            tile[(l4 * 4 + j) * 648 + base] = *reinterpret_cast<ushort*>(&hv);
        }
    }
    __syncthreads();
    const int ie = t >> 3;          // endpoint-in-block 0..31
    const int b  = t & 7;
    const int e  = ie >> 1, hh = ie & 1;
    const int d  = dest[e0 * 2 + ie];          // i = (e0+e)*2 + hh == e0*2 + ie
    const ushort* srcl = &tile[e * 648 + b * 80 + hh * 40];
    ushort* dst = xg + ((size_t)d * 8 + b) * 32;
#pragma unroll
    for (int j = 0; j < 4; ++j) {
        u32x4 q = *reinterpret_cast<const u32x4*>(srcl + j * 8);
        __builtin_nontemporal_store(q, reinterpret_cast<u32x4*>(dst + j * 8));
    }
}

// ---------- decode: linear reads of xg[v*6+slot][b][32], 2x MFMA MLP ----------
// grid.x = 2048: vblk = bx & 255, b = bx >> 8  (keeps the 8 b-blocks of one
// v-range on the SAME XCD: bx mod 8 unchanged -> their interleaved 64B reads
// of the same 512B chunks merge in that XCD's L2).
__global__ __launch_bounds__(256) void decode_mfma(
    const ushort* __restrict__ xg,
    const __hip_bfloat16* __restrict__ w1f, const float* __restrict__ b1,
    const __hip_bfloat16* __restrict__ w2f, const float* __restrict__ b2,
    float* __restrict__ out)
{
    __shared__ __align__(16) __hip_bfloat16 ys[64][104];  // 96 + 8 pad
    const int t    = threadIdx.x;
    const int l    = t & 63;
    const int wid  = t >> 6;
    const int bx   = blockIdx.x;
    const int b    = bx >> 8;
    const int v0   = (bx & 255) * 64 + wid * 16;
    const int lr   = l & 15;
    const int lg   = l >> 4;

    const ushort* xvb = xg + ((size_t)(v0 + lr) * 48 + b) * 32;   // + kk*256 + lg*8

    // ---- GEMM1: Y[16x96] = relu(X[16x192] @ W1 + b1) ----
    f32x4 acc[6];
#pragma unroll
    for (int nt = 0; nt < 6; ++nt) {
        float bv = b1[nt * 16 + lr];
        acc[nt] = (f32x4){bv, bv, bv, bv};
    }
#pragma unroll
    for (int kk = 0; kk < 6; ++kk) {
        bf16x8 a = *reinterpret_cast<const bf16x8*>(xvb + kk * 256 + lg * 8);
#pragma unroll
        for (int nt = 0; nt < 6; ++nt) {
            bf16x8 w = *reinterpret_cast<const bf16x8*>(w1f + ((size_t)((kk * 6 + nt) * 64 + l) * 8));
            acc[nt] = __builtin_amdgcn_mfma_f32_16x16x32_bf16(a, w, acc[nt], 0, 0, 0);
        }
    }
    // relu -> bf16 -> ys (D layout: row=(lg*4+r), col=lr)
#pragma unroll
    for (int nt = 0; nt < 6; ++nt) {
#pragma unroll
        for (int r = 0; r < 4; ++r) {
            ys[wid * 16 + lg * 4 + r][nt * 16 + lr] = __float2bfloat16(fmaxf(acc[nt][r], 0.0f));
        }
    }
    __syncthreads();   // ys cross-lane LDS writes -> GEMM2 A-fragment reads

    // ---- GEMM2: O[16x64] = relu(Y[16x96] @ W2 + b2) ----
    f32x4 acc2[4];
#pragma unroll
    for (int nt = 0; nt < 4; ++nt) {
        float bv = b2[nt * 16 + lr];
        acc2[nt] = (f32x4){bv, bv, bv, bv};
    }
#pragma unroll
    for (int kk = 0; kk < 3; ++kk) {
        bf16x8 a = *reinterpret_cast<const bf16x8*>(&ys[wid * 16 + lr][kk * 32 + lg * 8]);
#pragma unroll
        for (int nt = 0; nt < 4; ++nt) {
            bf16x8 w = *reinterpret_cast<const bf16x8*>(w2f + ((size_t)((kk * 4 + nt) * 64 + l) * 8));
            acc2[nt] = __builtin_amdgcn_mfma_f32_16x16x32_bf16(a, w, acc2[nt], 0, 0, 0);
        }
    }

    // ---- write out[b][o][v]: o = nt*16+lr, v = v0 + lg*4 + r (nontemporal streaming) ----
    const int vbase = v0 + lg * 4;
#pragma unroll
    for (int nt = 0; nt < 4; ++nt) {
        f32x4 o4;
#pragma unroll
        for (int r = 0; r < 4; ++r) o4[r] = fmaxf(acc2[nt][r], 0.0f);
        __builtin_nontemporal_store(o4,
            reinterpret_cast<f32x4*>(out + (((size_t)(b * OUTC + nt * 16 + lr)) << 14) + vbase));
    }
}

extern "C" void kernel_launch(void* const* d_in, const int* in_sizes, int n_in,
                              void* d_out, int out_size, void* d_ws, size_t ws_size,
                              hipStream_t stream) {
    const float* feat = (const float*)d_in[0];
    const int*   conn = (const int*)d_in[1];
    const float* W1   = (const float*)d_in[3];
    const float* b1   = (const float*)d_in[4];
    const float* W2   = (const float*)d_in[5];
    const float* b2   = (const float*)d_in[6];
    float* out = (float*)d_out;

    char* ws = (char*)d_ws;
    int* cnt     = (int*)ws;                                  // 64 KB
    int* buckets = (int*)(ws + 65536);                        // 384 KB
    int* dest    = (int*)(ws + 65536 + 393216);               // 384 KB
    __hip_bfloat16* w1f = (__hip_bfloat16*)(ws + 65536 + 2 * 393216);   // 36 KB
    __hip_bfloat16* w2f = w1f + 18432;                                  // 12 KB
    ushort* xg = (ushort*)(ws + 65536 + 2 * 393216 + 49152);  // 50.33 MB, [v*6+slot][b][32]

    prep_misc<<<96, 256, 0, stream>>>(W1, W2, w1f, w2f, cnt);
    bucket_fill<<<(TWOE + 255) / 256, 256, 0, stream>>>(conn, cnt, buckets);
    sort6_inv<<<(Vv + 255) / 256, 256, 0, stream>>>(buckets, dest);
    scatter_feats<<<Ee / 16, 256, 0, stream>>>(feat, dest, xg);
    decode_mfma<<<2048, 256, 0, stream>>>(xg, w1f, b1, w2f, b2, out);
}

// Round 8
// 89.468 us; speedup vs baseline: 1.4617x; 1.4617x over previous
//
#include <hip/hip_runtime.h>
#include <hip/hip_bf16.h>
#include <stdint.h>

namespace {
constexpr int Bb   = 8;
constexpr int Ff   = 64;
constexpr int Ee   = 49152;
constexpr int Vv   = 16384;
constexpr int TWOE = 2 * Ee;      // 98304
constexpr int MID  = 96;
constexpr int OUTC = 64;
}

typedef __attribute__((ext_vector_type(8))) short bf16x8;
typedef __attribute__((ext_vector_type(4))) float f32x4;
typedef __attribute__((ext_vector_type(4))) unsigned int u32x4;

// ---------- zero counters + pack weights into MFMA B-fragment order (one launch) ----------
__global__ void prep_misc(const float* __restrict__ W1, const float* __restrict__ W2,
                          __hip_bfloat16* __restrict__ w1f, __hip_bfloat16* __restrict__ w2f,
                          int* __restrict__ cnt) {
    int tid = blockIdx.x * 256 + threadIdx.x;   // 0 .. 24575
    if (tid < Vv) cnt[tid] = 0;
    if (tid < 18432) {
        int j = tid & 7, l = (tid >> 3) & 63, ft = tid >> 9;   // ft = kk*6+nt
        int kk = ft / 6, nt = ft - kk * 6;
        int k = kk * 32 + (l >> 4) * 8 + j;
        int n = nt * 16 + (l & 15);
        w1f[tid] = __float2bfloat16(W1[k * MID + n]);
    } else if (tid < 24576) {
        int t2 = tid - 18432;
        int j = t2 & 7, l = (t2 >> 3) & 63, ft = t2 >> 9;      // ft = kk*4+nt
        int kk = ft >> 2, nt = ft & 3;
        int k = kk * 32 + (l >> 4) * 8 + j;
        int n = nt * 16 + (l & 15);
        w2f[t2] = __float2bfloat16(W2[k * OUTC + n]);
    }
}

// ---------- build occurrence buckets ----------
__global__ void bucket_fill(const int* __restrict__ conn, int* __restrict__ cnt,
                            int* __restrict__ buckets) {
    int i = blockIdx.x * 256 + threadIdx.x;
    if (i >= TWOE) return;
    int v = conn[i];
    int pos = atomicAdd(&cnt[v], 1);
    if (pos < 6) buckets[v * 6 + pos] = i;
}

// ---------- sort the 6 indices per vertex, emit inverse perm dest[i] = v*6 + slot ----------
__global__ void sort6_inv(const int* __restrict__ buckets, int* __restrict__ dest) {
    int v = blockIdx.x * 256 + threadIdx.x;
    if (v >= Vv) return;
    int a[6];
#pragma unroll
    for (int k = 0; k < 6; ++k) a[k] = buckets[v * 6 + k];
#define CSWAP(x, y) { int lo = min(a[x], a[y]); int hi = max(a[x], a[y]); a[x] = lo; a[y] = hi; }
    CSWAP(1, 2) CSWAP(4, 5) CSWAP(0, 2) CSWAP(3, 5) CSWAP(0, 1) CSWAP(3, 4)
    CSWAP(2, 5) CSWAP(0, 3) CSWAP(1, 4) CSWAP(2, 4) CSWAP(1, 3) CSWAP(2, 3)
#undef CSWAP
#pragma unroll
    for (int k = 0; k < 6; ++k) dest[a[k]] = v * 6 + k;
}

// ---------- transpose + permute, batch-fused ----------
// Block = 16 e-values (32 endpoints). xg layout: [v*6+slot][b][32] bf16 -> each
// endpoint is ONE 512B aligned region. Drain: 32 consecutive lanes per region,
// lane r writes bytes [r*16, r*16+16) -> full 128B lines, perfectly coalesced.
__global__ __launch_bounds__(256) void scatter_feats(const float* __restrict__ feat,
                                                     const int* __restrict__ dest,
                                                     ushort* __restrict__ xg) {
    // tile ushort offset: off(e,hh,b,cc) = e*648 + hh*40 + b*80 + cc
    __shared__ __align__(16) ushort tile[16 * 648];   // 20.25 KB
    const int t  = threadIdx.x;
    const int e0 = blockIdx.x * 16;
    const int c  = t >> 2;          // channel 0..63
    const int l4 = t & 3;           // e-quad 0..3
    const int hc = c >> 5, cc = c & 31;
#pragma unroll
    for (int b = 0; b < 8; ++b) {
        float4 d = *reinterpret_cast<const float4*>(feat + ((size_t)b * Ff + c) * Ee + e0 + l4 * 4);
        int base = b * 80 + hc * 40 + cc;
        float vals[4] = {d.x, d.y, d.z, d.w};
#pragma unroll
        for (int j = 0; j < 4; ++j) {
            __hip_bfloat16 hv = __float2bfloat16(vals[j]);
            tile[(l4 * 4 + j) * 648 + base] = *reinterpret_cast<ushort*>(&hv);
        }
    }
    __syncthreads();
    // drain: 32 endpoints x 32 lanes x 16B = 4 iterations of 256 threads
#pragma unroll
    for (int it = 0; it < 4; ++it) {
        int task = it * 256 + t;        // 0..1023
        int ie = task >> 5;             // endpoint-in-block 0..31
        int r  = task & 31;             // 16B-chunk within 512B region
        int e  = ie >> 1, hh = ie & 1;
        int b  = r >> 2,  j  = r & 3;
        int d  = dest[e0 * 2 + ie];
        u32x4 q = *reinterpret_cast<const u32x4*>(&tile[e * 648 + hh * 40 + b * 80 + j * 8]);
        __builtin_nontemporal_store(q, reinterpret_cast<u32x4*>(xg + (size_t)d * 256 + r * 8));
    }
}

// ---------- decode: linear reads of xg[v*6+slot][b][32], 2x MFMA MLP ----------
// grid.x = 2048: vblk = bx & 255, b = bx >> 8 (keeps the 8 b-blocks of one
// v-range on the SAME XCD -> their interleaved 64B reads merge in L2).
__global__ __launch_bounds__(256) void decode_mfma(
    const ushort* __restrict__ xg,
    const __hip_bfloat16* __restrict__ w1f, const float* __restrict__ b1,
    const __hip_bfloat16* __restrict__ w2f, const float* __restrict__ b2,
    float* __restrict__ out)
{
    __shared__ __align__(16) __hip_bfloat16 ys[64][104];  // 96 + 8 pad
    const int t    = threadIdx.x;
    const int l    = t & 63;
    const int wid  = t >> 6;
    const int bx   = blockIdx.x;
    const int b    = bx >> 8;
    const int v0   = (bx & 255) * 64 + wid * 16;
    const int lr   = l & 15;
    const int lg   = l >> 4;

    const ushort* xvb = xg + ((size_t)(v0 + lr) * 48 + b) * 32;   // + kk*256 + lg*8

    // ---- GEMM1: Y[16x96] = relu(X[16x192] @ W1 + b1) ----
    f32x4 acc[6];
#pragma unroll
    for (int nt = 0; nt < 6; ++nt) {
        float bv = b1[nt * 16 + lr];
        acc[nt] = (f32x4){bv, bv, bv, bv};
    }
#pragma unroll
    for (int kk = 0; kk < 6; ++kk) {
        bf16x8 a = *reinterpret_cast<const bf16x8*>(xvb + kk * 256 + lg * 8);
#pragma unroll
        for (int nt = 0; nt < 6; ++nt) {
            bf16x8 w = *reinterpret_cast<const bf16x8*>(w1f + ((size_t)((kk * 6 + nt) * 64 + l) * 8));
            acc[nt] = __builtin_amdgcn_mfma_f32_16x16x32_bf16(a, w, acc[nt], 0, 0, 0);
        }
    }
    // relu -> bf16 -> ys (D layout: row=(lg*4+r), col=lr)
#pragma unroll
    for (int nt = 0; nt < 6; ++nt) {
#pragma unroll
        for (int r = 0; r < 4; ++r) {
            ys[wid * 16 + lg * 4 + r][nt * 16 + lr] = __float2bfloat16(fmaxf(acc[nt][r], 0.0f));
        }
    }
    __syncthreads();   // ys cross-lane LDS writes -> GEMM2 A-fragment reads

    // ---- GEMM2: O[16x64] = relu(Y[16x96] @ W2 + b2) ----
    f32x4 acc2[4];
#pragma unroll
    for (int nt = 0; nt < 4; ++nt) {
        float bv = b2[nt * 16 + lr];
        acc2[nt] = (f32x4){bv, bv, bv, bv};
    }
#pragma unroll
    for (int kk = 0; kk < 3; ++kk) {
        bf16x8 a = *reinterpret_cast<const bf16x8*>(&ys[wid * 16 + lr][kk * 32 + lg * 8]);
#pragma unroll
        for (int nt = 0; nt < 4; ++nt) {
            bf16x8 w = *reinterpret_cast<const bf16x8*>(w2f + ((size_t)((kk * 4 + nt) * 64 + l) * 8));
            acc2[nt] = __builtin_amdgcn_mfma_f32_16x16x32_bf16(a, w, acc2[nt], 0, 0, 0);
        }
    }

    // ---- write out[b][o][v]: o = nt*16+lr, v = v0 + lg*4 + r (nontemporal streaming) ----
    const int vbase = v0 + lg * 4;
#pragma unroll
    for (int nt = 0; nt < 4; ++nt) {
        f32x4 o4;
#pragma unroll
        for (int r = 0; r < 4; ++r) o4[r] = fmaxf(acc2[nt][r], 0.0f);
        __builtin_nontemporal_store(o4,
            reinterpret_cast<f32x4*>(out + (((size_t)(b * OUTC + nt * 16 + lr)) << 14) + vbase));
    }
}

extern "C" void kernel_launch(void* const* d_in, const int* in_sizes, int n_in,
                              void* d_out, int out_size, void* d_ws, size_t ws_size,
                              hipStream_t stream) {
    const float* feat = (const float*)d_in[0];
    const int*   conn = (const int*)d_in[1];
    const float* W1   = (const float*)d_in[3];
    const float* b1   = (const float*)d_in[4];
    const float* W2   = (const float*)d_in[5];
    const float* b2   = (const float*)d_in[6];
    float* out = (float*)d_out;

    char* ws = (char*)d_ws;
    int* cnt     = (int*)ws;                                  // 64 KB
    int* buckets = (int*)(ws + 65536);                        // 384 KB
    int* dest    = (int*)(ws + 65536 + 393216);               // 384 KB
    __hip_bfloat16* w1f = (__hip_bfloat16*)(ws + 65536 + 2 * 393216);   // 36 KB
    __hip_bfloat16* w2f = w1f + 18432;                                  // 12 KB
    ushort* xg = (ushort*)(ws + 65536 + 2 * 393216 + 49152);  // 50.33 MB, [v*6+slot][b][32]

    prep_misc<<<96, 256, 0, stream>>>(W1, W2, w1f, w2f, cnt);
    bucket_fill<<<(TWOE + 255) / 256, 256, 0, stream>>>(conn, cnt, buckets);
    sort6_inv<<<(Vv + 255) / 256, 256, 0, stream>>>(buckets, dest);
    scatter_feats<<<Ee / 16, 256, 0, stream>>>(feat, dest, xg);
    decode_mfma<<<2048, 256, 0, stream>>>(xg, w1f, b1, w2f, b2, out);
}

// Round 9
// 74.256 us; speedup vs baseline: 1.7612x; 1.2049x over previous
//
#include <hip/hip_runtime.h>
#include <hip/hip_bf16.h>
#include <stdint.h>

namespace {
constexpr int Bb   = 8;
constexpr int Ff   = 64;
constexpr int Ee   = 49152;
constexpr int Vv   = 16384;
constexpr int TWOE = 2 * Ee;      // 98304
constexpr int MID  = 96;
constexpr int OUTC = 64;
}

typedef __attribute__((ext_vector_type(8))) short bf16x8;
typedef __attribute__((ext_vector_type(4))) float f32x4;
typedef __attribute__((ext_vector_type(2))) float f32x2;
typedef __attribute__((ext_vector_type(4))) unsigned int u32x4;

// ---------- zero counters + pack weights into MFMA B-fragment order ----------
__global__ void prep_misc(const float* __restrict__ W1, const float* __restrict__ W2,
                          __hip_bfloat16* __restrict__ w1f, __hip_bfloat16* __restrict__ w2f,
                          int* __restrict__ cnt) {
    int tid = blockIdx.x * 256 + threadIdx.x;   // 0 .. 24575
    if (tid < Vv) cnt[tid] = 0;
    if (tid < 18432) {
        int j = tid & 7, l = (tid >> 3) & 63, ft = tid >> 9;   // ft = kk*6+nt
        int kk = ft / 6, nt = ft - kk * 6;
        int k = kk * 32 + (l >> 4) * 8 + j;
        int n = nt * 16 + (l & 15);
        w1f[tid] = __float2bfloat16(W1[k * MID + n]);
    } else if (tid < 24576) {
        int t2 = tid - 18432;
        int j = t2 & 7, l = (t2 >> 3) & 63, ft = t2 >> 9;      // ft = kk*4+nt
        int kk = ft >> 2, nt = ft & 3;
        int k = kk * 32 + (l >> 4) * 8 + j;
        int n = nt * 16 + (l & 15);
        w2f[t2] = __float2bfloat16(W2[k * OUTC + n]);
    }
}

// ---------- build occurrence buckets ----------
__global__ void bucket_fill(const int* __restrict__ conn, int* __restrict__ cnt,
                            int* __restrict__ buckets) {
    int i = blockIdx.x * 256 + threadIdx.x;
    if (i >= TWOE) return;
    int v = conn[i];
    int pos = atomicAdd(&cnt[v], 1);
    if (pos < 6) buckets[v * 6 + pos] = i;
}

// ---------- sort the 6 indices per vertex, emit inverse perm dest[i] = v*6 + slot ----------
__global__ void sort6_inv(const int* __restrict__ buckets, int* __restrict__ dest) {
    int v = blockIdx.x * 256 + threadIdx.x;
    if (v >= Vv) return;
    int a[6];
#pragma unroll
    for (int k = 0; k < 6; ++k) a[k] = buckets[v * 6 + k];
#define CSWAP(x, y) { int lo = min(a[x], a[y]); int hi = max(a[x], a[y]); a[x] = lo; a[y] = hi; }
    CSWAP(1, 2) CSWAP(4, 5) CSWAP(0, 2) CSWAP(3, 5) CSWAP(0, 1) CSWAP(3, 4)
    CSWAP(2, 5) CSWAP(0, 3) CSWAP(1, 4) CSWAP(2, 4) CSWAP(1, 3) CSWAP(2, 3)
#undef CSWAP
#pragma unroll
    for (int k = 0; k < 6; ++k) dest[a[k]] = v * 6 + k;
}

// ---------- transpose + permute, batch-PAIR fused ----------
// Block = 64 e-values x 64 channels x 2 batches (b = 2g+q). feat rows = 256B full
// lines. xg layout [g][v*6+slot][q][32] bf16: each endpoint owns one FULL 128B
// line, written by 8 lanes x 16B of one wave instruction (nt-safe, zero amp).
__global__ __launch_bounds__(256) void scatter_feats(const float* __restrict__ feat,
                                                     const int* __restrict__ dest,
                                                     ushort* __restrict__ xg) {
    __shared__ __align__(16) ushort tile[2][64][72];   // [q][e][c], 18.4 KB
    const int t  = threadIdx.x;
    const int e0 = blockIdx.x * 64;
    const int g  = blockIdx.y;
    const int c  = t >> 2;          // channel 0..63
    const int l4 = t & 3;           // e-quad selector
#pragma unroll
    for (int q = 0; q < 2; ++q) {
        const float* src = feat + ((size_t)(2 * g + q) * Ff + c) * Ee + e0;
#pragma unroll
        for (int k = 0; k < 4; ++k) {
            int e = k * 16 + l4 * 4;
            float4 d = *reinterpret_cast<const float4*>(src + e);
            __hip_bfloat16 h0 = __float2bfloat16(d.x);
            __hip_bfloat16 h1 = __float2bfloat16(d.y);
            __hip_bfloat16 h2 = __float2bfloat16(d.z);
            __hip_bfloat16 h3 = __float2bfloat16(d.w);
            tile[q][e + 0][c] = *reinterpret_cast<ushort*>(&h0);
            tile[q][e + 1][c] = *reinterpret_cast<ushort*>(&h1);
            tile[q][e + 2][c] = *reinterpret_cast<ushort*>(&h2);
            tile[q][e + 3][c] = *reinterpret_cast<ushort*>(&h3);
        }
    }
    __syncthreads();
    // drain: 128 endpoints x 8 chunks of 16B = 1024 tasks
    const size_t base_g = (size_t)g * ((size_t)Vv * 384);
#pragma unroll
    for (int it = 0; it < 4; ++it) {
        int task = it * 256 + t;
        int ie = task >> 3;             // endpoint-in-block 0..127
        int r  = task & 7;              // 16B chunk within 128B region
        int e  = ie >> 1, h = ie & 1;
        int q  = r >> 2,  j = r & 3;
        int d  = dest[e0 * 2 + ie];
        u32x4 qv = *reinterpret_cast<const u32x4*>(&tile[q][e][h * 32 + j * 8]);
        __builtin_nontemporal_store(qv,
            reinterpret_cast<u32x4*>(xg + base_g + (size_t)d * 64 + r * 8));
    }
}

// ---------- decode: block = 32 v x 2 q, dense 128B-granule reads, 2x MFMA MLP ----------
__global__ __launch_bounds__(256) void decode_mfma(
    const ushort* __restrict__ xg,
    const __hip_bfloat16* __restrict__ w1f, const float* __restrict__ b1,
    const __hip_bfloat16* __restrict__ w2f, const float* __restrict__ b2,
    float* __restrict__ out)
{
    __shared__ __align__(16) __hip_bfloat16 ys[64][104];  // 96 + 8 pad
    const int t    = threadIdx.x;
    const int l    = t & 63;
    const int wid  = t >> 6;
    const int g    = blockIdx.y;
    const int vw   = blockIdx.x * 32 + wid * 8;   // wave's v base (8 v x 2 q = 16 rows)
    const int lr   = l & 15;
    const int lg   = l >> 4;

    // A row lr -> (v = vw + (lr>>1), q = lr&1)
    const ushort* xa = xg + (size_t)g * ((size_t)Vv * 384)
                     + ((size_t)(vw + (lr >> 1)) * 6) * 64 + (lr & 1) * 32 + lg * 8;

    // ---- GEMM1: Y[16x96] = relu(X[16x192] @ W1 + b1) ----
    f32x4 acc[6];
#pragma unroll
    for (int nt = 0; nt < 6; ++nt) {
        float bv = b1[nt * 16 + lr];
        acc[nt] = (f32x4){bv, bv, bv, bv};
    }
#pragma unroll
    for (int kk = 0; kk < 6; ++kk) {              // kk == slot
        bf16x8 a = *reinterpret_cast<const bf16x8*>(xa + kk * 64);
#pragma unroll
        for (int nt = 0; nt < 6; ++nt) {
            bf16x8 w = *reinterpret_cast<const bf16x8*>(w1f + ((size_t)((kk * 6 + nt) * 64 + l) * 8));
            acc[nt] = __builtin_amdgcn_mfma_f32_16x16x32_bf16(a, w, acc[nt], 0, 0, 0);
        }
    }
    // relu -> bf16 -> ys (D layout: row=(lg*4+r), col=lr); row semantics carried through
#pragma unroll
    for (int nt = 0; nt < 6; ++nt) {
#pragma unroll
        for (int r = 0; r < 4; ++r) {
            ys[wid * 16 + lg * 4 + r][nt * 16 + lr] = __float2bfloat16(fmaxf(acc[nt][r], 0.0f));
        }
    }
    __syncthreads();   // ys cross-lane LDS writes -> GEMM2 A-fragment reads

    // ---- GEMM2: O[16x64] = relu(Y[16x96] @ W2 + b2) ----
    f32x4 acc2[4];
#pragma unroll
    for (int nt = 0; nt < 4; ++nt) {
        float bv = b2[nt * 16 + lr];
        acc2[nt] = (f32x4){bv, bv, bv, bv};
    }
#pragma unroll
    for (int kk = 0; kk < 3; ++kk) {
        bf16x8 a = *reinterpret_cast<const bf16x8*>(&ys[wid * 16 + lr][kk * 32 + lg * 8]);
#pragma unroll
        for (int nt = 0; nt < 4; ++nt) {
            bf16x8 w = *reinterpret_cast<const bf16x8*>(w2f + ((size_t)((kk * 4 + nt) * 64 + l) * 8));
            acc2[nt] = __builtin_amdgcn_mfma_f32_16x16x32_bf16(a, w, acc2[nt], 0, 0, 0);
        }
    }

    // ---- out write: D row = lg*4+r -> (v = vw + 2*lg + (r>>1), q = r&1), col -> o ----
    // plain (non-nt) float2 stores; each (b,o) 128B line fully covered by this block.
#pragma unroll
    for (int nt = 0; nt < 4; ++nt) {
        int o = nt * 16 + lr;
        f32x2 p0 = {fmaxf(acc2[nt][0], 0.0f), fmaxf(acc2[nt][2], 0.0f)};  // q=0: v, v+1
        f32x2 p1 = {fmaxf(acc2[nt][1], 0.0f), fmaxf(acc2[nt][3], 0.0f)};  // q=1: v, v+1
        int vv = vw + 2 * lg;
        *reinterpret_cast<f32x2*>(out + ((size_t)((2 * g + 0) * OUTC + o) << 14) + vv) = p0;
        *reinterpret_cast<f32x2*>(out + ((size_t)((2 * g + 1) * OUTC + o) << 14) + vv) = p1;
    }
}

extern "C" void kernel_launch(void* const* d_in, const int* in_sizes, int n_in,
                              void* d_out, int out_size, void* d_ws, size_t ws_size,
                              hipStream_t stream) {
    const float* feat = (const float*)d_in[0];
    const int*   conn = (const int*)d_in[1];
    const float* W1   = (const float*)d_in[3];
    const float* b1   = (const float*)d_in[4];
    const float* W2   = (const float*)d_in[5];
    const float* b2   = (const float*)d_in[6];
    float* out = (float*)d_out;

    char* ws = (char*)d_ws;
    int* cnt     = (int*)ws;                                  // 64 KB
    int* buckets = (int*)(ws + 65536);                        // 384 KB
    int* dest    = (int*)(ws + 65536 + 393216);               // 384 KB
    __hip_bfloat16* w1f = (__hip_bfloat16*)(ws + 65536 + 2 * 393216);   // 36 KB
    __hip_bfloat16* w2f = w1f + 18432;                                  // 12 KB
    ushort* xg = (ushort*)(ws + 65536 + 2 * 393216 + 49152);  // 50.33 MB, [g][v*6+s][q][32]

    prep_misc<<<96, 256, 0, stream>>>(W1, W2, w1f, w2f, cnt);
    bucket_fill<<<(TWOE + 255) / 256, 256, 0, stream>>>(conn, cnt, buckets);
    sort6_inv<<<(Vv + 255) / 256, 256, 0, stream>>>(buckets, dest);
    scatter_feats<<<dim3(Ee / 64, 4), 256, 0, stream>>>(feat, dest, xg);
    decode_mfma<<<dim3(Vv / 32, 4), 256, 0, stream>>>(xg, w1f, b1, w2f, b2, out);
}